// Round 1
// baseline (837.974 us; speedup 1.0000x reference)
//
#include <hip/hip_runtime.h>

using bf16x8 = __attribute__((ext_vector_type(8))) __bf16;
using f32x4  = __attribute__((ext_vector_type(4))) float;

#define AS1 __attribute__((address_space(1)))
#define AS3 __attribute__((address_space(3)))

__device__ __forceinline__ unsigned short f2bf(float f) {
    unsigned int x = __float_as_uint(f);
    x += 0x7fffu + ((x >> 16) & 1u);   // RNE
    return (unsigned short)(x >> 16);
}

// ---------------- convert x fp32 -> bf16 ----------------
__global__ void cvt_f32_bf16_kernel(const float4* __restrict__ in, ushort4* __restrict__ out, int n4) {
    int stride = gridDim.x * blockDim.x;
    for (int i = blockIdx.x * blockDim.x + threadIdx.x; i < n4; i += stride) {
        float4 v = in[i];
        ushort4 o;
        o.x = f2bf(v.x); o.y = f2bf(v.y); o.z = f2bf(v.z); o.w = f2bf(v.w);
        out[i] = o;
    }
}

// ---------------- transpose W (K x N) fp32 -> Wt (N x K) bf16 ----------------
__global__ void transpose_f32_bf16_kernel(const float* __restrict__ W, unsigned short* __restrict__ Wt,
                                          int K, int N) {
    __shared__ float tile[32][33];
    int n0 = blockIdx.x << 5, k0 = blockIdx.y << 5;
    int tx = threadIdx.x, ty = threadIdx.y;
#pragma unroll
    for (int i = 0; i < 32; i += 8)
        tile[ty + i][tx] = W[(size_t)(k0 + ty + i) * N + (n0 + tx)];
    __syncthreads();
#pragma unroll
    for (int i = 0; i < 32; i += 8)
        Wt[(size_t)(n0 + ty + i) * K + (k0 + tx)] = f2bf(tile[tx][ty + i]);
}

// ---------------- GEMM: C[M,N] = A[M,K] * Bt[N,K]^T, bf16 in, fp32 acc ----------------
// m97 structure: 128x128 tile, BK=64, 4 waves (2x2), 4x4 16x16x32 frags/wave,
// global_load_lds width 16, st-style XOR swizzle (byte ^= (row&7)<<4) on both sides.
__device__ __forceinline__ void stage_tile_128x64(const unsigned short* g, int ldK,
                                                  unsigned short* lds, int tid) {
#pragma unroll
    for (int r = 0; r < 4; ++r) {
        int i = (r << 8) + tid;              // 0..1023 : 16B chunks
        int row = i >> 3;                    // 128 rows
        int colb = (i & 7) << 4;             // byte col in 128B row
        int srcb = row * (ldK << 1) + (colb ^ ((row & 7) << 4));  // inverse-swizzled source
        __builtin_amdgcn_global_load_lds(
            (AS1 unsigned int*)(unsigned long long)((const char*)g + srcb),
            (AS3 unsigned int*)((char*)lds + (i << 4)),
            16, 0, 0);
    }
}

__device__ __forceinline__ bf16x8 lds_read_swz(const unsigned short* base, int row, int kbyte) {
    int off = (row << 7) + (kbyte ^ ((row & 7) << 4));
    return *(const bf16x8*)((const char*)base + off);
}

template <int OUTMODE>  // 0: bf16 out, 1: fp32 out + bias
__global__ __launch_bounds__(256, 2)
void gemm_bt_kernel(const unsigned short* __restrict__ A, const unsigned short* __restrict__ Bt,
                    unsigned short* __restrict__ obf, float* __restrict__ of32,
                    const float* __restrict__ bias, int M, int N, int K) {
    __shared__ unsigned short As[128 * 64];
    __shared__ unsigned short Bs[128 * 64];
    int tid = threadIdx.x;
    int lane = tid & 63, w = tid >> 6;
    int wm = w >> 1, wn = w & 1;
    int m0 = blockIdx.y << 7, n0 = blockIdx.x << 7;
    const unsigned short* Ag = A + (size_t)m0 * K;
    const unsigned short* Bg = Bt + (size_t)n0 * K;

    f32x4 zz = {0.f, 0.f, 0.f, 0.f};
    f32x4 acc[4][4];
#pragma unroll
    for (int a = 0; a < 4; ++a)
#pragma unroll
        for (int b = 0; b < 4; ++b) acc[a][b] = zz;

    for (int kb = 0; kb < K; kb += 64) {
        stage_tile_128x64(Ag + kb, K, As, tid);
        stage_tile_128x64(Bg + kb, K, Bs, tid);
        __syncthreads();
#pragma unroll
        for (int ks = 0; ks < 2; ++ks) {
            int kbyte = (ks << 6) + ((lane >> 4) << 4);
            bf16x8 af[4], bfr[4];
#pragma unroll
            for (int f = 0; f < 4; ++f)
                af[f] = lds_read_swz(As, (wm << 6) + (f << 4) + (lane & 15), kbyte);
#pragma unroll
            for (int f = 0; f < 4; ++f)
                bfr[f] = lds_read_swz(Bs, (wn << 6) + (f << 4) + (lane & 15), kbyte);
#pragma unroll
            for (int fm = 0; fm < 4; ++fm)
#pragma unroll
                for (int fn = 0; fn < 4; ++fn)
                    acc[fm][fn] = __builtin_amdgcn_mfma_f32_16x16x32_bf16(af[fm], bfr[fn], acc[fm][fn], 0, 0, 0);
        }
        __syncthreads();
    }

    int rbase = m0 + (wm << 6) + ((lane >> 4) << 2);
    int cbase = n0 + (wn << 6) + (lane & 15);
    if (OUTMODE == 0) {
#pragma unroll
        for (int fm = 0; fm < 4; ++fm)
#pragma unroll
            for (int j = 0; j < 4; ++j) {
                size_t ro = (size_t)(rbase + (fm << 4) + j) * N;
#pragma unroll
                for (int fn = 0; fn < 4; ++fn)
                    obf[ro + cbase + (fn << 4)] = f2bf(acc[fm][fn][j]);
            }
    } else {
        float bv[4];
#pragma unroll
        for (int fn = 0; fn < 4; ++fn) bv[fn] = bias[cbase + (fn << 4)];
#pragma unroll
        for (int fm = 0; fm < 4; ++fm)
#pragma unroll
            for (int j = 0; j < 4; ++j) {
                size_t ro = (size_t)(rbase + (fm << 4) + j) * N;
#pragma unroll
                for (int fn = 0; fn < 4; ++fn)
                    of32[ro + cbase + (fn << 4)] = acc[fm][fn][j] + bv[fn];
            }
    }
}

// ---------------- covariance S[bh][c][e] = sum_n k[n,c]*q[n,e]  + channel norms ----------------
// grid (128 bh, 7 token-chunks of 448), block 256, 6x6 register tile per thread, fp32 atomics.
__global__ __launch_bounds__(256)
void cov_norm_kernel(const unsigned short* __restrict__ qkv, float* __restrict__ S,
                     float* __restrict__ qn2, float* __restrict__ kn2) {
    int bh = blockIdx.x;
    int b = bh >> 3, h = bh & 7;
    int tok0 = blockIdx.y * 448;
    __shared__ float qf[16][96];
    __shared__ float kf[16][96];
    int tid = threadIdx.x;
    int ti = tid >> 4, tj = tid & 15;
    int ti6 = ti * 6, tj6 = tj * 6;

    float acc[6][6];
#pragma unroll
    for (int i = 0; i < 6; ++i)
#pragma unroll
        for (int j = 0; j < 6; ++j) acc[i][j] = 0.f;
    float qn = 0.f, kn = 0.f;

    const unsigned int* qg = (const unsigned int*)qkv;  // qkv row = 1152 uints

    for (int t0 = 0; t0 < 28; ++t0) {
        int tokBase = b * 3136 + tok0 + (t0 << 4);
#pragma unroll
        for (int r = 0; r < 6; ++r) {
            int i2 = (r << 8) + tid;        // 0..1535 ; first 768 = q, next 768 = k
            int isK = (i2 >= 768);
            int j = i2 - (isK ? 768 : 0);
            int row = j / 48, ep = j % 48;
            unsigned int u = qg[(size_t)(tokBase + row) * 1152 + (isK ? (384 + h * 48) : (h * 48)) + ep];
            float2 v;
            v.x = __uint_as_float(u << 16);
            v.y = __uint_as_float(u & 0xffff0000u);
            if (isK) *(float2*)&kf[row][ep << 1] = v;
            else     *(float2*)&qf[row][ep << 1] = v;
        }
        __syncthreads();
#pragma unroll
        for (int tt = 0; tt < 16; ++tt) {
            float2 k01 = *(const float2*)&kf[tt][ti6];
            float2 k23 = *(const float2*)&kf[tt][ti6 + 2];
            float2 k45 = *(const float2*)&kf[tt][ti6 + 4];
            float2 q01 = *(const float2*)&qf[tt][tj6];
            float2 q23 = *(const float2*)&qf[tt][tj6 + 2];
            float2 q45 = *(const float2*)&qf[tt][tj6 + 4];
            float kv[6] = {k01.x, k01.y, k23.x, k23.y, k45.x, k45.y};
            float qv[6] = {q01.x, q01.y, q23.x, q23.y, q45.x, q45.y};
#pragma unroll
            for (int i = 0; i < 6; ++i)
#pragma unroll
                for (int j = 0; j < 6; ++j) acc[i][j] = fmaf(kv[i], qv[j], acc[i][j]);
            if (tid < 96) {
                float a = qf[tt][tid]; qn = fmaf(a, a, qn);
                float c = kf[tt][tid]; kn = fmaf(c, c, kn);
            }
        }
        __syncthreads();
    }

    float* Sb = S + (size_t)bh * 9216;
#pragma unroll
    for (int i = 0; i < 6; ++i)
#pragma unroll
        for (int j = 0; j < 6; ++j)
            atomicAdd(&Sb[(ti6 + i) * 96 + tj6 + j], acc[i][j]);
    if (tid < 96) {
        atomicAdd(&qn2[bh * 96 + tid], qn);
        atomicAdd(&kn2[bh * 96 + tid], kn);
    }
}

// ---------------- softmax over e of S[c,e]/(||k_c||*||q_e||)*temp[h] -> bf16 attn ----------------
__global__ __launch_bounds__(128)
void softmax_kernel(const float* __restrict__ S, const float* __restrict__ qn2,
                    const float* __restrict__ kn2, const float* __restrict__ temp,
                    unsigned short* __restrict__ attnb) {
    int bh = blockIdx.x, h = bh & 7;
    __shared__ float Sl[96 * 97];
    __shared__ float qinv[96];
    int tid = threadIdx.x;
    const float* Sg = S + (size_t)bh * 9216;
    for (int i = tid; i < 9216; i += 128) Sl[(i / 96) * 97 + (i % 96)] = Sg[i];
    if (tid < 96) qinv[tid] = 1.f / fmaxf(sqrtf(qn2[bh * 96 + tid]), 1e-12f);
    __syncthreads();
    if (tid < 96) {
        int c = tid;
        float scale = (1.f / fmaxf(sqrtf(kn2[bh * 96 + c]), 1e-12f)) * temp[h];
        float* row = &Sl[c * 97];
        float mx = -3.4e38f;
        for (int e = 0; e < 96; ++e) {
            float v = row[e] * scale * qinv[e];
            row[e] = v;
            mx = fmaxf(mx, v);
        }
        float s = 0.f;
        for (int e = 0; e < 96; ++e) {
            float p = __expf(row[e] - mx);
            row[e] = p;
            s += p;
        }
        float inv = 1.f / s;
        unsigned short* ab = attnb + (size_t)bh * 9216 + c * 96;
        for (int e = 0; e < 96; ++e) ab[e] = f2bf(row[e] * inv);
    }
}

// ---------------- Y[n, h*96+c] = sum_e attn[bh][c][e] * v[n][e]  (MFMA, token-major) ----------------
__global__ __launch_bounds__(256)
void attn_v_kernel(const unsigned short* __restrict__ qkv, const unsigned short* __restrict__ attnb,
                   unsigned short* __restrict__ Y) {
    int n0 = blockIdx.x << 6;   // 64-token tile
    int bh = blockIdx.y;
    int b = bh >> 3, h = bh & 7;
    __shared__ unsigned short Asm[96 * 104];  // attn rows (padded)
    __shared__ unsigned short Vs[64 * 104];   // V rows (padded)
    int tid = threadIdx.x;
    int lane = tid & 63, w = tid >> 6;

    const unsigned int* ag = (const unsigned int*)(attnb + (size_t)bh * 9216);
#pragma unroll
    for (int r = 0; r < 18; ++r) {
        int i2 = (r << 8) + tid;            // 4608 uints
        int c = i2 / 48, ep = i2 % 48;
        *(unsigned int*)&Asm[c * 104 + (ep << 1)] = ag[i2];
    }
    size_t vbase = (size_t)(b * 3136 + n0) * 1152 + 768 + h * 48;  // uint index
    const unsigned int* vg = (const unsigned int*)qkv;
#pragma unroll
    for (int r = 0; r < 12; ++r) {
        int i2 = (r << 8) + tid;            // 3072 uints
        int row = i2 / 48, ep = i2 % 48;
        *(unsigned int*)&Vs[row * 104 + (ep << 1)] = vg[vbase + (size_t)row * 1152 + ep];
    }
    __syncthreads();

    f32x4 zz = {0.f, 0.f, 0.f, 0.f};
    f32x4 acc[6];
#pragma unroll
    for (int f = 0; f < 6; ++f) acc[f] = zz;

#pragma unroll
    for (int ks = 0; ks < 3; ++ks) {
        int kbyte = (ks << 6) + ((lane >> 4) << 4);
        bf16x8 av = *(const bf16x8*)((const char*)Vs + ((w << 4) + (lane & 15)) * 208 + kbyte);
#pragma unroll
        for (int fn = 0; fn < 6; ++fn) {
            bf16x8 bv = *(const bf16x8*)((const char*)Asm + ((fn << 4) + (lane & 15)) * 208 + kbyte);
            acc[fn] = __builtin_amdgcn_mfma_f32_16x16x32_bf16(av, bv, acc[fn], 0, 0, 0);
        }
    }

    int rlocal = n0 + (w << 4) + ((lane >> 4) << 2);
#pragma unroll
    for (int fn = 0; fn < 6; ++fn)
#pragma unroll
        for (int j = 0; j < 4; ++j)
            Y[(size_t)(b * 3136 + rlocal + j) * 768 + h * 96 + (fn << 4) + (lane & 15)] = f2bf(acc[fn][j]);
}

// ---------------- launch ----------------
extern "C" void kernel_launch(void* const* d_in, const int* in_sizes, int n_in,
                              void* d_out, int out_size, void* d_ws, size_t ws_size,
                              hipStream_t stream) {
    const float* x     = (const float*)d_in[0];
    const float* Wqkv  = (const float*)d_in[1];
    const float* temp  = (const float*)d_in[2];
    const float* Wproj = (const float*)d_in[3];
    const float* bproj = (const float*)d_in[4];
    float* out = (float*)d_out;
    char* ws = (char*)d_ws;

    // workspace layout (bytes)
    unsigned short* xbf    = (unsigned short*)(ws);                 //  77,070,336
    unsigned short* qkvbf  = (unsigned short*)(ws + 77070336);      // 231,211,008
    unsigned short* wqkvt  = (unsigned short*)(ws + 308281344);     //   3,538,944
    unsigned short* wprojt = (unsigned short*)(ws + 311820288);     //   1,179,648
    float*          Sbuf   = (float*)        (ws + 312999936);      //   4,718,592
    float*          qn2    = (float*)        (ws + 317718528);      //      49,152
    float*          kn2    = (float*)        (ws + 317767680);      //      49,152
    unsigned short* attnb  = (unsigned short*)(ws + 317816832);     //   2,359,296 (end 320,176,128)
    unsigned short* ybf    = xbf;  // alias: x_bf16 dead after GEMM1

    hipMemsetAsync(Sbuf, 0, 4718592 + 49152 + 49152, stream);

    cvt_f32_bf16_kernel<<<2048, 256, 0, stream>>>((const float4*)x, (ushort4*)xbf, 38535168 / 4);
    transpose_f32_bf16_kernel<<<dim3(72, 24), dim3(32, 8), 0, stream>>>(Wqkv, wqkvt, 768, 2304);
    transpose_f32_bf16_kernel<<<dim3(24, 24), dim3(32, 8), 0, stream>>>(Wproj, wprojt, 768, 768);

    // qkv = x @ Wqkv   [50176 x 2304], bf16 out
    gemm_bt_kernel<0><<<dim3(18, 392), 256, 0, stream>>>(xbf, wqkvt, qkvbf, nullptr, nullptr,
                                                         50176, 2304, 768);
    // S, norms
    cov_norm_kernel<<<dim3(128, 7), 256, 0, stream>>>(qkvbf, Sbuf, qn2, kn2);
    // attn = softmax(S / (|k||q|) * temp)
    softmax_kernel<<<128, 128, 0, stream>>>(Sbuf, qn2, kn2, temp, attnb);
    // Y = V * attn^T  (token-major)
    attn_v_kernel<<<dim3(49, 128), 256, 0, stream>>>(qkvbf, attnb, ybf);
    // out = Y @ Wproj + b   fp32
    gemm_bt_kernel<1><<<dim3(6, 392), 256, 0, stream>>>(ybf, wprojt, nullptr, out, bproj,
                                                        50176, 768, 768);
}

// Round 2
// 451.875 us; speedup vs baseline: 1.8544x; 1.8544x over previous
//
#include <hip/hip_runtime.h>

using bf16x8 = __attribute__((ext_vector_type(8))) __bf16;
using f32x4  = __attribute__((ext_vector_type(4))) float;

#define AS1 __attribute__((address_space(1)))
#define AS3 __attribute__((address_space(3)))

__device__ __forceinline__ unsigned short f2bf(float f) {
    unsigned int x = __float_as_uint(f);
    x += 0x7fffu + ((x >> 16) & 1u);   // RNE
    return (unsigned short)(x >> 16);
}

// ---------------- convert x fp32 -> bf16 ----------------
__global__ void cvt_f32_bf16_kernel(const float4* __restrict__ in, ushort4* __restrict__ out, int n4) {
    int stride = gridDim.x * blockDim.x;
    for (int i = blockIdx.x * blockDim.x + threadIdx.x; i < n4; i += stride) {
        float4 v = in[i];
        ushort4 o;
        o.x = f2bf(v.x); o.y = f2bf(v.y); o.z = f2bf(v.z); o.w = f2bf(v.w);
        out[i] = o;
    }
}

// ---------------- transpose W (K x N) fp32 -> Wt (N x K) bf16 ----------------
__global__ void transpose_f32_bf16_kernel(const float* __restrict__ W, unsigned short* __restrict__ Wt,
                                          int K, int N) {
    __shared__ float tile[32][33];
    int n0 = blockIdx.x << 5, k0 = blockIdx.y << 5;
    int tx = threadIdx.x, ty = threadIdx.y;
#pragma unroll
    for (int i = 0; i < 32; i += 8)
        tile[ty + i][tx] = W[(size_t)(k0 + ty + i) * N + (n0 + tx)];
    __syncthreads();
#pragma unroll
    for (int i = 0; i < 32; i += 8)
        Wt[(size_t)(n0 + ty + i) * K + (k0 + tx)] = f2bf(tile[tx][ty + i]);
}

// ---------------- GEMM: C[M,N] = A[M,K] * Bt[N,K]^T, bf16 in, fp32 acc ----------------
// m97 structure: 128x128 tile, BK=64, 4 waves (2x2), 4x4 16x16x32 frags/wave,
// global_load_lds width 16, XOR swizzle (byte ^= (row&7)<<4) on both sides.
__device__ __forceinline__ void stage_tile_128x64(const unsigned short* g, int ldK,
                                                  unsigned short* lds, int tid) {
#pragma unroll
    for (int r = 0; r < 4; ++r) {
        int i = (r << 8) + tid;              // 0..1023 : 16B chunks
        int row = i >> 3;                    // 128 rows
        int colb = (i & 7) << 4;             // byte col in 128B row
        int srcb = row * (ldK << 1) + (colb ^ ((row & 7) << 4));  // inverse-swizzled source
        __builtin_amdgcn_global_load_lds(
            (AS1 unsigned int*)(unsigned long long)((const char*)g + srcb),
            (AS3 unsigned int*)((char*)lds + (i << 4)),
            16, 0, 0);
    }
}

__device__ __forceinline__ bf16x8 lds_read_swz(const unsigned short* base, int row, int kbyte) {
    int off = (row << 7) + (kbyte ^ ((row & 7) << 4));
    return *(const bf16x8*)((const char*)base + off);
}

template <int OUTMODE>  // 0: bf16 out, 1: fp32 out + bias
__global__ __launch_bounds__(256, 2)
void gemm_bt_kernel(const unsigned short* __restrict__ A, const unsigned short* __restrict__ Bt,
                    unsigned short* __restrict__ obf, float* __restrict__ of32,
                    const float* __restrict__ bias, int M, int N, int K) {
    __shared__ unsigned short As[128 * 64];
    __shared__ unsigned short Bs[128 * 64];
    int tid = threadIdx.x;
    int lane = tid & 63, w = tid >> 6;
    int wm = w >> 1, wn = w & 1;
    int m0 = blockIdx.y << 7, n0 = blockIdx.x << 7;
    const unsigned short* Ag = A + (size_t)m0 * K;
    const unsigned short* Bg = Bt + (size_t)n0 * K;

    f32x4 zz = {0.f, 0.f, 0.f, 0.f};
    f32x4 acc[4][4];
#pragma unroll
    for (int a = 0; a < 4; ++a)
#pragma unroll
        for (int b = 0; b < 4; ++b) acc[a][b] = zz;

    for (int kb = 0; kb < K; kb += 64) {
        stage_tile_128x64(Ag + kb, K, As, tid);
        stage_tile_128x64(Bg + kb, K, Bs, tid);
        __syncthreads();
#pragma unroll
        for (int ks = 0; ks < 2; ++ks) {
            int kbyte = (ks << 6) + ((lane >> 4) << 4);
            bf16x8 af[4], bfr[4];
#pragma unroll
            for (int f = 0; f < 4; ++f)
                af[f] = lds_read_swz(As, (wm << 6) + (f << 4) + (lane & 15), kbyte);
#pragma unroll
            for (int f = 0; f < 4; ++f)
                bfr[f] = lds_read_swz(Bs, (wn << 6) + (f << 4) + (lane & 15), kbyte);
#pragma unroll
            for (int fm = 0; fm < 4; ++fm)
#pragma unroll
                for (int fn = 0; fn < 4; ++fn)
                    acc[fm][fn] = __builtin_amdgcn_mfma_f32_16x16x32_bf16(af[fm], bfr[fn], acc[fm][fn], 0, 0, 0);
        }
        __syncthreads();
    }

    int rbase = m0 + (wm << 6) + ((lane >> 4) << 2);
    int cbase = n0 + (wn << 6) + (lane & 15);
    if (OUTMODE == 0) {
#pragma unroll
        for (int fm = 0; fm < 4; ++fm)
#pragma unroll
            for (int j = 0; j < 4; ++j) {
                size_t ro = (size_t)(rbase + (fm << 4) + j) * N;
#pragma unroll
                for (int fn = 0; fn < 4; ++fn)
                    obf[ro + cbase + (fn << 4)] = f2bf(acc[fm][fn][j]);
            }
    } else {
        float bv[4];
#pragma unroll
        for (int fn = 0; fn < 4; ++fn) bv[fn] = bias[cbase + (fn << 4)];
#pragma unroll
        for (int fm = 0; fm < 4; ++fm)
#pragma unroll
            for (int j = 0; j < 4; ++j) {
                size_t ro = (size_t)(rbase + (fm << 4) + j) * N;
#pragma unroll
                for (int fn = 0; fn < 4; ++fn)
                    of32[ro + cbase + (fn << 4)] = acc[fm][fn][j] + bv[fn];
            }
    }
}

// ---------------- covariance via MFMA: S[bh][c][e] = sum_n k[n,c]*q[n,e], + channel norms ----
// grid (128 bh, 7 token-chunks of 448), 256 threads = 4 waves, each wave a 48x48 quadrant.
// Per 32-token step: reg-staged transposed LDS write (lane-rotated scatter), 1 MFMA K-step.
__global__ __launch_bounds__(256)
void cov_mfma_kernel(const unsigned short* __restrict__ qkv, float* __restrict__ S,
                     float* __restrict__ qn2, float* __restrict__ kn2) {
    __shared__ unsigned short Kl[96 * 40];   // [channel][token], stride 40 ushorts (80B, 16B-aligned)
    __shared__ unsigned short Ql[96 * 40];
    int bh = blockIdx.x;
    int b = bh >> 3, h = bh & 7;
    int tok0 = blockIdx.y * 448;
    int tid = threadIdx.x;
    int lane = tid & 63, w = tid >> 6;
    int wr = w & 1, wc = w >> 1;
    int rot = tid & 7;

    f32x4 zz = {0.f, 0.f, 0.f, 0.f};
    f32x4 acc[3][3];
#pragma unroll
    for (int a = 0; a < 3; ++a)
#pragma unroll
        for (int c = 0; c < 3; ++c) acc[a][c] = zz;
    float qn = 0.f, kn = 0.f;

    const uint4* qg = (const uint4*)qkv;   // qkv row = 288 uint4 (2304 ushorts)

    for (int step = 0; step < 14; ++step) {
        int tokBase = b * 3136 + tok0 + (step << 5);
        __syncthreads();   // previous step's LDS reads done before overwrite
#pragma unroll
        for (int r = 0; r < 3; ++r) {
            int idx = (r << 8) + tid;          // 0..767 ; 0..383 = Q, 384..767 = K
            int isK = idx >= 384;
            int j = isK ? idx - 384 : idx;
            int tok = j / 12, c = j % 12;      // c: which uint4 of the 96-ch row
            uint4 u = qg[(size_t)(tokBase + tok) * 288 + h * 12 + (isK ? 96 : 0) + c];
            unsigned short* dst = isK ? Kl : Ql;
            const unsigned short* us = (const unsigned short*)&u;
#pragma unroll
            for (int i = 0; i < 8; ++i) {
                int e = (i + rot) & 7;          // rotated write order -> spread banks
                dst[(c * 8 + e) * 40 + tok] = us[e];
            }
        }
        __syncthreads();
        // channel norms straight from staged LDS (q: threads 0..95, k: threads 128..223)
        if (tid < 96) {
#pragma unroll
            for (int t = 0; t < 4; ++t) {
                bf16x8 v = *(const bf16x8*)((const char*)Ql + tid * 80 + (t << 4));
#pragma unroll
                for (int i = 0; i < 8; ++i) { float f = (float)v[i]; qn = fmaf(f, f, qn); }
            }
        } else if (tid >= 128 && tid < 224) {
            int c = tid - 128;
#pragma unroll
            for (int t = 0; t < 4; ++t) {
                bf16x8 v = *(const bf16x8*)((const char*)Kl + c * 80 + (t << 4));
#pragma unroll
                for (int i = 0; i < 8; ++i) { float f = (float)v[i]; kn = fmaf(f, f, kn); }
            }
        }
        // MFMA: one K=32 step
        int kbyte = (lane >> 4) << 4;
        bf16x8 af[3], bfv[3];
#pragma unroll
        for (int f = 0; f < 3; ++f)
            af[f] = *(const bf16x8*)((const char*)Kl + (wr * 48 + f * 16 + (lane & 15)) * 80 + kbyte);
#pragma unroll
        for (int f = 0; f < 3; ++f)
            bfv[f] = *(const bf16x8*)((const char*)Ql + (wc * 48 + f * 16 + (lane & 15)) * 80 + kbyte);
#pragma unroll
        for (int fm = 0; fm < 3; ++fm)
#pragma unroll
            for (int fn = 0; fn < 3; ++fn)
                acc[fm][fn] = __builtin_amdgcn_mfma_f32_16x16x32_bf16(af[fm], bfv[fn], acc[fm][fn], 0, 0, 0);
    }

    // accumulate partial S: D row = k-channel, col = q-channel
    float* Sb = S + (size_t)bh * 9216;
    int rloc = wr * 48 + ((lane >> 4) << 2);
    int cloc = wc * 48 + (lane & 15);
#pragma unroll
    for (int fm = 0; fm < 3; ++fm)
#pragma unroll
        for (int fn = 0; fn < 3; ++fn)
#pragma unroll
            for (int j = 0; j < 4; ++j)
                atomicAdd(&Sb[(rloc + fm * 16 + j) * 96 + cloc + fn * 16], acc[fm][fn][j]);
    if (tid < 96) atomicAdd(&qn2[bh * 96 + tid], qn);
    if (tid >= 128 && tid < 224) atomicAdd(&kn2[bh * 96 + tid - 128], kn);
}

// ---------------- softmax over e of S[c,e]/(||k_c||*||q_e||)*temp[h] -> bf16 attn ----------------
__global__ __launch_bounds__(128)
void softmax_kernel(const float* __restrict__ S, const float* __restrict__ qn2,
                    const float* __restrict__ kn2, const float* __restrict__ temp,
                    unsigned short* __restrict__ attnb) {
    int bh = blockIdx.x, h = bh & 7;
    __shared__ float Sl[96 * 97];
    __shared__ float qinv[96];
    int tid = threadIdx.x;
    const float* Sg = S + (size_t)bh * 9216;
    for (int i = tid; i < 9216; i += 128) Sl[(i / 96) * 97 + (i % 96)] = Sg[i];
    if (tid < 96) qinv[tid] = 1.f / fmaxf(sqrtf(qn2[bh * 96 + tid]), 1e-12f);
    __syncthreads();
    if (tid < 96) {
        int c = tid;
        float scale = (1.f / fmaxf(sqrtf(kn2[bh * 96 + c]), 1e-12f)) * temp[h];
        float* row = &Sl[c * 97];
        float mx = -3.4e38f;
        for (int e = 0; e < 96; ++e) {
            float v = row[e] * scale * qinv[e];
            row[e] = v;
            mx = fmaxf(mx, v);
        }
        float s = 0.f;
        for (int e = 0; e < 96; ++e) {
            float p = __expf(row[e] - mx);
            row[e] = p;
            s += p;
        }
        float inv = 1.f / s;
        unsigned short* ab = attnb + (size_t)bh * 9216 + c * 96;
        for (int e = 0; e < 96; ++e) ab[e] = f2bf(row[e] * inv);
    }
}

// ---------------- Y[n, h*96+c] = sum_e attn[bh][c][e] * v[n][e]  (MFMA, token-major) ----------------
__global__ __launch_bounds__(256)
void attn_v_kernel(const unsigned short* __restrict__ qkv, const unsigned short* __restrict__ attnb,
                   unsigned short* __restrict__ Y) {
    int n0 = blockIdx.x << 6;   // 64-token tile
    int bh = blockIdx.y;
    int b = bh >> 3, h = bh & 7;
    __shared__ unsigned short Asm[96 * 104];  // attn rows (padded)
    __shared__ unsigned short Vs[64 * 104];   // V rows (padded)
    int tid = threadIdx.x;
    int lane = tid & 63, w = tid >> 6;

    const unsigned int* ag = (const unsigned int*)(attnb + (size_t)bh * 9216);
#pragma unroll
    for (int r = 0; r < 18; ++r) {
        int i2 = (r << 8) + tid;            // 4608 uints
        int c = i2 / 48, ep = i2 % 48;
        *(unsigned int*)&Asm[c * 104 + (ep << 1)] = ag[i2];
    }
    size_t vbase = (size_t)(b * 3136 + n0) * 1152 + 768 + h * 48;  // uint index
    const unsigned int* vg = (const unsigned int*)qkv;
#pragma unroll
    for (int r = 0; r < 12; ++r) {
        int i2 = (r << 8) + tid;            // 3072 uints
        int row = i2 / 48, ep = i2 % 48;
        *(unsigned int*)&Vs[row * 104 + (ep << 1)] = vg[vbase + (size_t)row * 1152 + ep];
    }
    __syncthreads();

    f32x4 zz = {0.f, 0.f, 0.f, 0.f};
    f32x4 acc[6];
#pragma unroll
    for (int f = 0; f < 6; ++f) acc[f] = zz;

#pragma unroll
    for (int ks = 0; ks < 3; ++ks) {
        int kbyte = (ks << 6) + ((lane >> 4) << 4);
        bf16x8 av = *(const bf16x8*)((const char*)Vs + ((w << 4) + (lane & 15)) * 208 + kbyte);
#pragma unroll
        for (int fn = 0; fn < 6; ++fn) {
            bf16x8 bv = *(const bf16x8*)((const char*)Asm + ((fn << 4) + (lane & 15)) * 208 + kbyte);
            acc[fn] = __builtin_amdgcn_mfma_f32_16x16x32_bf16(av, bv, acc[fn], 0, 0, 0);
        }
    }

    int rlocal = n0 + (w << 4) + ((lane >> 4) << 2);
#pragma unroll
    for (int fn = 0; fn < 6; ++fn)
#pragma unroll
        for (int j = 0; j < 4; ++j)
            Y[(size_t)(b * 3136 + rlocal + j) * 768 + h * 96 + (fn << 4) + (lane & 15)] = f2bf(acc[fn][j]);
}

// ---------------- launch ----------------
extern "C" void kernel_launch(void* const* d_in, const int* in_sizes, int n_in,
                              void* d_out, int out_size, void* d_ws, size_t ws_size,
                              hipStream_t stream) {
    const float* x     = (const float*)d_in[0];
    const float* Wqkv  = (const float*)d_in[1];
    const float* temp  = (const float*)d_in[2];
    const float* Wproj = (const float*)d_in[3];
    const float* bproj = (const float*)d_in[4];
    float* out = (float*)d_out;
    char* ws = (char*)d_ws;

    // workspace layout (bytes)
    unsigned short* xbf    = (unsigned short*)(ws);                 //  77,070,336
    unsigned short* qkvbf  = (unsigned short*)(ws + 77070336);      // 231,211,008
    unsigned short* wqkvt  = (unsigned short*)(ws + 308281344);     //   3,538,944
    unsigned short* wprojt = (unsigned short*)(ws + 311820288);     //   1,179,648
    float*          Sbuf   = (float*)        (ws + 312999936);      //   4,718,592
    float*          qn2    = (float*)        (ws + 317718528);      //      49,152
    float*          kn2    = (float*)        (ws + 317767680);      //      49,152
    unsigned short* attnb  = (unsigned short*)(ws + 317816832);     //   2,359,296 (end 320,176,128)
    unsigned short* ybf    = xbf;  // alias: x_bf16 dead after GEMM1

    hipMemsetAsync(Sbuf, 0, 4718592 + 49152 + 49152, stream);

    cvt_f32_bf16_kernel<<<2048, 256, 0, stream>>>((const float4*)x, (ushort4*)xbf, 38535168 / 4);
    transpose_f32_bf16_kernel<<<dim3(72, 24), dim3(32, 8), 0, stream>>>(Wqkv, wqkvt, 768, 2304);
    transpose_f32_bf16_kernel<<<dim3(24, 24), dim3(32, 8), 0, stream>>>(Wproj, wprojt, 768, 768);

    // qkv = x @ Wqkv   [50176 x 2304], bf16 out
    gemm_bt_kernel<0><<<dim3(18, 392), 256, 0, stream>>>(xbf, wqkvt, qkvbf, nullptr, nullptr,
                                                         50176, 2304, 768);
    // S = K^T Q (per bh), + channel norms
    cov_mfma_kernel<<<dim3(128, 7), 256, 0, stream>>>(qkvbf, Sbuf, qn2, kn2);
    // attn = softmax(S / (|k||q|) * temp)
    softmax_kernel<<<128, 128, 0, stream>>>(Sbuf, qn2, kn2, temp, attnb);
    // Y = V * attn^T  (token-major)
    attn_v_kernel<<<dim3(49, 128), 256, 0, stream>>>(qkvbf, attnb, ybf);
    // out = Y @ Wproj + b   fp32
    gemm_bt_kernel<1><<<dim3(6, 392), 256, 0, stream>>>(ybf, wprojt, nullptr, out, bproj,
                                                        50176, 768, 768);
}